// Round 2
// baseline (38225.760 us; speedup 1.0000x reference)
//
#include <hip/hip_runtime.h>
#include <hip/hip_bf16.h>
#include <math.h>

#define TT 512
#define BB 128
#define DD 256
#define HH 512
#define EPSF 1e-7f
#define NBG 8
#define NKS 32

typedef unsigned int u32;
typedef unsigned short u16;
typedef __attribute__((ext_vector_type(8))) short bf16x8;
typedef __attribute__((ext_vector_type(4))) float f32x4;

__device__ __forceinline__ float bf_lo(u32 u){ return __uint_as_float(u << 16); }
__device__ __forceinline__ float bf_hi(u32 u){ return __uint_as_float(u & 0xffff0000u); }

__device__ __forceinline__ u16 f2b(float x){
  __hip_bfloat16 b = __float2bfloat16(x);
  union { __hip_bfloat16 h; u16 u; } c; c.h = b; return c.u;
}

__device__ __forceinline__ bf16x8 as_b8(uint4 u){
  union { uint4 a; bf16x8 b; } c; c.a = u; return c.b;
}

// ---------------------------------------------------------------------------
// Setup: concrete-dropout masks zx/zh (f32), combined bias, bf16 Wx/Wh copies,
// and zeroed sync counters. Segmented flat-index kernel.
// ---------------------------------------------------------------------------
__global__ void setup_kernel(const float* __restrict__ ux, const float* __restrict__ uh,
                             const float* __restrict__ p_logit,
                             const float* __restrict__ bx, const float* __restrict__ bh,
                             const float* __restrict__ Wx, const float* __restrict__ Wh,
                             float* __restrict__ zx, float* __restrict__ zh,
                             float* __restrict__ bias,
                             u16* __restrict__ wxb, u16* __restrict__ whb,
                             u32* __restrict__ cnt){
  const int i = blockIdx.x*256 + threadIdx.x;
  const float p = 1.0f/(1.0f+expf(-p_logit[0]));
  const float lp = logf(p+EPSF) - logf(1.0f-p+EPSF);
  const float inv1mp = 1.0f/(1.0f-p);
  const int NZX = 4*BB*DD;            // 131072
  const int S1 = NZX;                 // zx end
  const int S2 = S1 + 4*BB*HH;        // 393216  zh end
  const int S3 = S2 + 4*HH;           // 395264  bias end
  const int S4 = S3 + 4*HH*DD;        // 919552  wxb end
  const int S5 = S4 + 4*HH*HH;        // 1968128 whb end
  const int S6 = S5 + NBG*TT;         // 1972224 cnt end
  if (i < S1){
    float u = ux[i];
    float l = (lp + logf(u+EPSF) - logf(1.0f-u+EPSF)) * 10.0f;  // /TEMP
    zx[i] = (1.0f - 1.0f/(1.0f+expf(-l))) * inv1mp;
  } else if (i < S2){
    int j = i - S1;
    float u = uh[j];
    float l = (lp + logf(u+EPSF) - logf(1.0f-u+EPSF)) * 10.0f;
    zh[j] = (1.0f - 1.0f/(1.0f+expf(-l))) * inv1mp;
  } else if (i < S3){
    int j = i - S2;
    bias[j] = bx[j] + bh[j];
  } else if (i < S4){
    int j = i - S3;
    wxb[j] = f2b(Wx[j]);
  } else if (i < S5){
    int j = i - S4;
    whb[j] = f2b(Wh[j]);
  } else if (i < S6){
    cnt[i - S5] = 0u;
  }
}

// ---------------------------------------------------------------------------
// xim[t][g][b][d] = bf16(input[t][b][d] * zx[g][b][d])  -- 8 elems/thread
// ---------------------------------------------------------------------------
__global__ void xim_kernel(const float* __restrict__ input, const float* __restrict__ zx,
                           u16* __restrict__ xim){
  const int i = blockIdx.x*256 + threadIdx.x;   // group of 8 elems
  const int base = i << 3;
  const int d = base & (DD-1);
  const int rest = base >> 8;          // (t*4+g)*128 + b
  const int b = rest & 127;
  const int tg = rest >> 7;
  const int g = tg & 3, t = tg >> 2;
  const float* ip = input + ((size_t)t*BB + b)*DD + d;
  const float* zp = zx + ((size_t)g*BB + b)*DD + d;
  float4 x0 = *(const float4*)ip;
  float4 x1 = *(const float4*)(ip+4);
  float4 z0 = *(const float4*)zp;
  float4 z1 = *(const float4*)(zp+4);
  union { u16 s[8]; uint4 v; } o;
  o.s[0]=f2b(x0.x*z0.x); o.s[1]=f2b(x0.y*z0.y); o.s[2]=f2b(x0.z*z0.z); o.s[3]=f2b(x0.w*z0.w);
  o.s[4]=f2b(x1.x*z1.x); o.s[5]=f2b(x1.y*z1.y); o.s[6]=f2b(x1.z*z1.z); o.s[7]=f2b(x1.w*z1.w);
  *(uint4*)(xim + base) = o.v;
}

// ---------------------------------------------------------------------------
// Persistent LSTM: 256 blocks = 8 b-groups(16 b) x 32 k-slices(16 k),
// 512 threads = 8 waves = (gate 0..3) x (h-half 0..1).
// Wh/Wx B-fragments register-resident; A-frags (xim, hm) loaded straight
// from global; per-b-group atomic-counter barrier; hm double-buffered.
// ---------------------------------------------------------------------------
__global__ __launch_bounds__(512, 2)
void lstm_persist(const u16* __restrict__ xim,   // [T][4][B][D]
                  const u16* __restrict__ whb,   // [4][H][H]
                  const u16* __restrict__ wxb,   // [4][H][D]
                  const float* __restrict__ zh,  // [4][B][H]
                  const float* __restrict__ bias,// [4][H]
                  u16* __restrict__ hmg,         // [2][NBG][4][16][H]
                  u32* __restrict__ cnt,         // [NBG][T]
                  float* __restrict__ hn,        // [T][B][H]
                  float* __restrict__ htc)       // [2][B][H]
{
  __shared__ float pl[8][16][16];
  __shared__ float pad_force[13312];   // cap residency clumping at 2 blocks/CU

  const int bid = blockIdx.x;
  const int bg = bid & 7, ks = bid >> 3;
  const int b0 = bg*16, k0 = ks*16;
  const int tid = threadIdx.x;
  const int wid = tid >> 6, lane = tid & 63;
  const int g = wid & 3, qh = wid >> 2;
  const int arow = lane & 15;          // A row (b) and B col (k)
  const int kq = lane >> 4;            // 0..3 (k-within-chunk group)

  if (cnt[0] == 0xdeadbeefu) pad_force[tid] = 1.f;  // never true; keeps LDS alloc

  // ---- prologue: weights into registers ----
  uint4 whf[8], wxf[4];
  #pragma unroll
  for (int c = 0; c < 8; c++)
    whf[c] = *(const uint4*)(whb + (((size_t)g*HH + k0 + arow)*HH + qh*256 + c*32 + kq*8));
  #pragma unroll
  for (int c = 0; c < 4; c++)
    wxf[c] = *(const uint4*)(wxb + (((size_t)g*HH + k0 + arow)*DD + qh*128 + c*32 + kq*8));

  const int ebl = tid >> 4, ekl = tid & 15;   // epilogue mapping (tid<256)
  float bias4[4] = {0,0,0,0}, zhe[4] = {0,0,0,0};
  if (tid < 256){
    #pragma unroll
    for (int gg = 0; gg < 4; gg++){
      bias4[gg] = bias[gg*HH + k0 + ekl];
      zhe[gg]   = zh[((size_t)gg*BB + b0 + ebl)*HH + k0 + ekl];
    }
  }
  float creg = 0.0f;

  for (int t = 0; t < TT; t++){
    // prefetch x A-frags (independent of the barrier -> latency hides in spin)
    uint4 xa[4];
    #pragma unroll
    for (int c = 0; c < 4; c++)
      xa[c] = *(const uint4*)(xim + ((((size_t)t*4 + g)*BB + b0 + arow)*DD
                                     + qh*128 + c*32 + kq*8));

    if (t > 0){
      if (tid == 0){
        while (__hip_atomic_load(&cnt[bg*TT + (t-1)], __ATOMIC_ACQUIRE,
                                 __HIP_MEMORY_SCOPE_AGENT) < (u32)NKS)
          __builtin_amdgcn_s_sleep(1);
      }
      __syncthreads();
      __threadfence();          // acquire: make peers' hm writes visible
    }

    f32x4 acc = {0.f, 0.f, 0.f, 0.f};
    #pragma unroll
    for (int c = 0; c < 4; c++)
      acc = __builtin_amdgcn_mfma_f32_16x16x32_bf16(as_b8(xa[c]), as_b8(wxf[c]), acc, 0, 0, 0);

    if (t > 0){
      const u16* hb = hmg + ((size_t)((t-1)&1)*NBG + bg)*4*16*HH;
      #pragma unroll
      for (int c = 0; c < 8; c++){
        uint4 ha = *(const uint4*)(hb + ((g*16 + arow)*HH + qh*256 + c*32 + kq*8));
        acc = __builtin_amdgcn_mfma_f32_16x16x32_bf16(as_b8(ha), as_b8(whf[c]), acc, 0, 0, 0);
      }
    }

    #pragma unroll
    for (int r = 0; r < 4; r++)
      pl[wid][kq*4 + r][arow] = acc[r];
    __syncthreads();

    if (tid < 256){
      float gv[4];
      #pragma unroll
      for (int gg = 0; gg < 4; gg++)
        gv[gg] = pl[gg][ebl][ekl] + pl[4+gg][ebl][ekl] + bias4[gg];
      float iv = 1.f/(1.f + __expf(-gv[0]));
      float fv = 1.f/(1.f + __expf(-gv[1]));
      float ov = 1.f/(1.f + __expf(-gv[2]));
      float e2g = __expf(2.f*gv[3]);
      float gc = 1.f - 2.f/(e2g + 1.f);          // tanh
      creg = fv*creg + iv*gc;
      float e2c = __expf(2.f*creg);
      float th = 1.f - 2.f/(e2c + 1.f);
      float hv = ov*th;
      const size_t ci = (size_t)(b0 + ebl)*HH + k0 + ekl;
      hn[(size_t)t*BB*HH + ci] = hv;
      u16* hw = hmg + ((size_t)(t&1)*NBG + bg)*4*16*HH;
      #pragma unroll
      for (int gg = 0; gg < 4; gg++)
        hw[(gg*16 + ebl)*HH + k0 + ekl] = f2b(hv * zhe[gg]);
      if (t == TT-1){
        htc[ci] = hv;
        htc[(size_t)BB*HH + ci] = creg;
      }
    }

    __threadfence();            // release: flush hm/out writes agent-wide
    __syncthreads();
    if (tid == 0)
      __hip_atomic_fetch_add(&cnt[bg*TT + t], 1u, __ATOMIC_RELEASE,
                             __HIP_MEMORY_SCOPE_AGENT);
  }
}

// ---------------------------------------------------------------------------
extern "C" void kernel_launch(void* const* d_in, const int* in_sizes, int n_in,
                              void* d_out, int out_size, void* d_ws, size_t ws_size,
                              hipStream_t stream){
  const float* input   = (const float*)d_in[0];
  const float* ux      = (const float*)d_in[1];
  const float* uh      = (const float*)d_in[2];
  const float* p_logit = (const float*)d_in[3];
  const float* Wx      = (const float*)d_in[4];
  const float* bx      = (const float*)d_in[5];
  const float* Wh      = (const float*)d_in[6];
  const float* bh      = (const float*)d_in[7];

  char* ws = (char*)d_ws;
  const size_t o_zx  = 0;                        // 4*B*D f32      = 524288
  const size_t o_zh  = o_zx  + 524288;           // 4*B*H f32      = 1048576
  const size_t o_b   = o_zh  + 1048576;          // 4*H f32        = 8192
  const size_t o_wxb = o_b   + 8192;             // 4*H*D bf16     = 1048576
  const size_t o_whb = o_wxb + 1048576;          // 4*H*H bf16     = 2097152
  const size_t o_xim = o_whb + 2097152;          // T*4*B*D bf16   = 134217728
  const size_t o_hmg = o_xim + 134217728;        // 2*8*4*16*H bf16= 2097152
  const size_t o_cnt = o_hmg + 2097152;          // 8*T u32        = 16384
  const size_t need  = o_cnt + 16384;
  if (ws_size < need) return;

  float* zx   = (float*)(ws + o_zx);
  float* zh   = (float*)(ws + o_zh);
  float* bias = (float*)(ws + o_b);
  u16*   wxb  = (u16*)(ws + o_wxb);
  u16*   whb  = (u16*)(ws + o_whb);
  u16*   xim  = (u16*)(ws + o_xim);
  u16*   hmg  = (u16*)(ws + o_hmg);
  u32*   cnt  = (u32*)(ws + o_cnt);

  float* out_hn = (float*)d_out;
  float* out_ht = out_hn + (size_t)TT*BB*HH;

  setup_kernel<<<7704, 256, 0, stream>>>(ux, uh, p_logit, bx, bh, Wx, Wh,
                                         zx, zh, bias, wxb, whb, cnt);
  xim_kernel<<<32768, 256, 0, stream>>>(input, zx, xim);
  lstm_persist<<<256, 512, 0, stream>>>(xim, whb, wxb, zh, bias,
                                        hmg, cnt, out_hn, out_ht);
}

// Round 3
// 2170.104 us; speedup vs baseline: 17.6147x; 17.6147x over previous
//
#include <hip/hip_runtime.h>
#include <hip/hip_bf16.h>
#include <math.h>

#define TT 512
#define BB 128
#define DD 256
#define HH 512
#define EPSF 1e-7f
#define NBG 8     // b-groups of 16 rows (independent LSTM chains)
#define NKS 16    // k-slices of 32 cols per b-group

typedef unsigned int u32;
typedef unsigned short u16;
typedef __attribute__((ext_vector_type(8))) short bf16x8;
typedef __attribute__((ext_vector_type(4))) float f32x4;
typedef __attribute__((ext_vector_type(4))) u32 u32x4;

__device__ __forceinline__ u16 f2b(float x){
  __hip_bfloat16 b = __float2bfloat16(x);
  union { __hip_bfloat16 h; u16 u; } c; c.h = b; return c.u;
}
__device__ __forceinline__ bf16x8 as_b8(u32x4 u){
  union { u32x4 a; bf16x8 b; } c; c.a = u; return c.b;
}
// system-scope (MALL-coherent) 16B store/load: bypass L1+L2, no wbl2/inv needed
__device__ __forceinline__ void st16_sys(void* p, u32x4 v){
  asm volatile("global_store_dwordx4 %0, %1, off sc0 sc1" :: "v"(p), "v"(v) : "memory");
}
__device__ __forceinline__ u32x4 ld16_sys(const void* p){
  u32x4 r;
  asm volatile("global_load_dwordx4 %0, %1, off sc0 sc1" : "=v"(r) : "v"(p) : "memory");
  return r;
}

// ---------------------------------------------------------------------------
// Setup: masks zx/zh, combined bias, bf16 Wx/Wh, zeroed sync counters.
// ---------------------------------------------------------------------------
__global__ void setup_kernel(const float* __restrict__ ux, const float* __restrict__ uh,
                             const float* __restrict__ p_logit,
                             const float* __restrict__ bx, const float* __restrict__ bh,
                             const float* __restrict__ Wx, const float* __restrict__ Wh,
                             float* __restrict__ zx, float* __restrict__ zh,
                             float* __restrict__ bias,
                             u16* __restrict__ wxb, u16* __restrict__ whb,
                             u32* __restrict__ cnt){
  const int i = blockIdx.x*256 + threadIdx.x;
  const float p = 1.0f/(1.0f+expf(-p_logit[0]));
  const float lp = logf(p+EPSF) - logf(1.0f-p+EPSF);
  const float inv1mp = 1.0f/(1.0f-p);
  const int S1 = 4*BB*DD;             // zx end      131072
  const int S2 = S1 + 4*BB*HH;        // zh end      393216
  const int S3 = S2 + 4*HH;           // bias end    395264
  const int S4 = S3 + 4*HH*DD;        // wxb end     919552
  const int S5 = S4 + 4*HH*HH;        // whb end     1968128
  const int S6 = S5 + NBG*TT;         // cnt end     1972224
  if (i < S1){
    float u = ux[i];
    float l = (lp + logf(u+EPSF) - logf(1.0f-u+EPSF)) * 10.0f;  // /TEMP
    zx[i] = (1.0f - 1.0f/(1.0f+expf(-l))) * inv1mp;
  } else if (i < S2){
    int j = i - S1;
    float u = uh[j];
    float l = (lp + logf(u+EPSF) - logf(1.0f-u+EPSF)) * 10.0f;
    zh[j] = (1.0f - 1.0f/(1.0f+expf(-l))) * inv1mp;
  } else if (i < S3){
    int j = i - S2;
    bias[j] = bx[j] + bh[j];
  } else if (i < S4){
    int j = i - S3;
    wxb[j] = f2b(Wx[j]);
  } else if (i < S5){
    int j = i - S4;
    whb[j] = f2b(Wh[j]);
  } else if (i < S6){
    cnt[i - S5] = 0u;
  }
}

// ---------------------------------------------------------------------------
// xim[t][g][b][d] = bf16(input[t][b][d] * zx[g][b][d]); input read once.
// ---------------------------------------------------------------------------
__global__ void xim_kernel(const float* __restrict__ input, const float* __restrict__ zx,
                           u16* __restrict__ xim){
  const int i = blockIdx.x*256 + threadIdx.x;   // (t,b,d-octet), T*B*D/8 total
  const int d = (i & 31) * 8;
  const int rest = i >> 5;             // t*BB + b
  const int b = rest & (BB-1);
  const int t = rest >> 7;
  const float* ip = input + ((size_t)t*BB + b)*DD + d;
  const float4 x0 = *(const float4*)ip;
  const float4 x1 = *(const float4*)(ip+4);
  #pragma unroll
  for (int g = 0; g < 4; g++){
    const float* zp = zx + ((size_t)g*BB + b)*DD + d;
    const float4 z0 = *(const float4*)zp;
    const float4 z1 = *(const float4*)(zp+4);
    union { u16 s[8]; uint4 v; } o;
    o.s[0]=f2b(x0.x*z0.x); o.s[1]=f2b(x0.y*z0.y); o.s[2]=f2b(x0.z*z0.z); o.s[3]=f2b(x0.w*z0.w);
    o.s[4]=f2b(x1.x*z1.x); o.s[5]=f2b(x1.y*z1.y); o.s[6]=f2b(x1.z*z1.z); o.s[7]=f2b(x1.w*z1.w);
    *(uint4*)(xim + (((size_t)t*4 + g)*BB + b)*DD + d) = o.v;
  }
}

// ---------------------------------------------------------------------------
// Persistent LSTM: 128 blocks = 8 b-groups(16 b) x 16 k-slices(32 k).
// 512 threads = 8 waves = (gate g) x (K-half qh). Weights register-resident.
// hm exchange through MALL via sc0/sc1 ops; relaxed flag atomics; zero
// cache-maintenance instructions in the loop.
// ---------------------------------------------------------------------------
__global__ __launch_bounds__(512, 2)
void lstm_persist(const u16* __restrict__ xim,   // [T][4][B][D]
                  const u16* __restrict__ whb,   // [4][H][H]
                  const u16* __restrict__ wxb,   // [4][H][D]
                  const float* __restrict__ zh,  // [4][B][H]
                  const float* __restrict__ bias,// [4][H]
                  u16* __restrict__ hmg,         // [2][NBG][4][16][H]
                  u32* __restrict__ cnt,         // [NBG][T]
                  float* __restrict__ hn,        // [T][B][H]
                  float* __restrict__ htc)       // [2][B][H]
{
  __shared__ float pl[8][16][32];   // partial gates [wid][b][k]
  __shared__ u16 hml[4][16][32];    // masked-h tile for coalesced writeout

  const int bid = blockIdx.x;
  const int bg = bid & 7, ks = bid >> 3;
  const int b0 = bg*16, k0 = ks*32;
  const int tid = threadIdx.x;
  const int wid = tid >> 6, lane = tid & 63;
  const int g = wid & 3, qh = wid >> 2;
  const int arow = lane & 15, kq = lane >> 4;

  // ---- weights into registers ----
  u32x4 whf[2][8], wxf[2][4];
  #pragma unroll
  for (int nt = 0; nt < 2; nt++){
    #pragma unroll
    for (int c = 0; c < 8; c++)
      whf[nt][c] = *(const u32x4*)(whb + (((size_t)g*HH + k0 + nt*16 + arow)*HH
                                          + qh*256 + c*32 + kq*8));
    #pragma unroll
    for (int c = 0; c < 4; c++)
      wxf[nt][c] = *(const u32x4*)(wxb + (((size_t)g*HH + k0 + nt*16 + arow)*DD
                                          + qh*128 + c*32 + kq*8));
  }

  const int ebl = tid >> 5, ekl = tid & 31;   // epilogue (b-local, k-local)
  float bias4[4], zhe[4];
  #pragma unroll
  for (int gg = 0; gg < 4; gg++){
    bias4[gg] = bias[gg*HH + k0 + ekl];
    zhe[gg]   = zh[((size_t)gg*BB + b0 + ebl)*HH + k0 + ekl];
  }
  float creg = 0.0f;

  for (int t = 0; t < TT; t++){
    // prefetch x A-frags before the spin (latency hides in the wait)
    u32x4 xa[4];
    #pragma unroll
    for (int c = 0; c < 4; c++)
      xa[c] = *(const u32x4*)(xim + ((((size_t)t*4 + g)*BB + b0 + arow)*DD
                                     + qh*128 + c*32 + kq*8));

    if (t > 0){
      if (tid == 0){
        while (__hip_atomic_load(&cnt[bg*TT + (t-1)], __ATOMIC_RELAXED,
                                 __HIP_MEMORY_SCOPE_AGENT) < (u32)NKS)
          __builtin_amdgcn_s_sleep(2);
      }
      __syncthreads();
    }

    f32x4 acc0 = {0.f,0.f,0.f,0.f}, acc1 = {0.f,0.f,0.f,0.f};

    if (t > 0){
      const u16* hb = hmg + ((size_t)((t-1)&1)*NBG + bg)*(4*16*HH);
      u32x4 ha[8];
      #pragma unroll
      for (int c = 0; c < 8; c++)
        ha[c] = ld16_sys(hb + ((g*16 + arow)*HH + qh*256 + c*32 + kq*8));
      asm volatile("s_waitcnt vmcnt(0)" ::: "memory");
      __builtin_amdgcn_sched_barrier(0);
      #pragma unroll
      for (int c = 0; c < 4; c++){
        acc0 = __builtin_amdgcn_mfma_f32_16x16x32_bf16(as_b8(xa[c]), as_b8(wxf[0][c]), acc0, 0,0,0);
        acc1 = __builtin_amdgcn_mfma_f32_16x16x32_bf16(as_b8(xa[c]), as_b8(wxf[1][c]), acc1, 0,0,0);
      }
      #pragma unroll
      for (int c = 0; c < 8; c++){
        acc0 = __builtin_amdgcn_mfma_f32_16x16x32_bf16(as_b8(ha[c]), as_b8(whf[0][c]), acc0, 0,0,0);
        acc1 = __builtin_amdgcn_mfma_f32_16x16x32_bf16(as_b8(ha[c]), as_b8(whf[1][c]), acc1, 0,0,0);
      }
    } else {
      #pragma unroll
      for (int c = 0; c < 4; c++){
        acc0 = __builtin_amdgcn_mfma_f32_16x16x32_bf16(as_b8(xa[c]), as_b8(wxf[0][c]), acc0, 0,0,0);
        acc1 = __builtin_amdgcn_mfma_f32_16x16x32_bf16(as_b8(xa[c]), as_b8(wxf[1][c]), acc1, 0,0,0);
      }
    }

    #pragma unroll
    for (int r = 0; r < 4; r++){
      pl[wid][kq*4 + r][arow]      = acc0[r];
      pl[wid][kq*4 + r][16 + arow] = acc1[r];
    }
    __syncthreads();

    { // epilogue: all 512 threads, one (b,k) cell each
      float gv[4];
      #pragma unroll
      for (int gg = 0; gg < 4; gg++)
        gv[gg] = pl[gg][ebl][ekl] + pl[4+gg][ebl][ekl] + bias4[gg];
      float iv = 1.f/(1.f + __expf(-gv[0]));
      float fv = 1.f/(1.f + __expf(-gv[1]));
      float ov = 1.f/(1.f + __expf(-gv[2]));
      float e2g = __expf(2.f*gv[3]);
      float gc = 1.f - 2.f/(e2g + 1.f);          // tanh(g)
      creg = fv*creg + iv*gc;
      float e2c = __expf(2.f*creg);
      float th = 1.f - 2.f/(e2c + 1.f);          // tanh(c)
      float hv = ov*th;
      const size_t ci = (size_t)(b0 + ebl)*HH + k0 + ekl;
      hn[(size_t)t*BB*HH + ci] = hv;
      #pragma unroll
      for (int gg = 0; gg < 4; gg++)
        hml[gg][ebl][ekl] = f2b(hv * zhe[gg]);
      if (t == TT-1){
        htc[ci] = hv;
        htc[(size_t)BB*HH + ci] = creg;
      }
    }
    __syncthreads();

    // coalesced hm writeout: 256 threads x 16B, system scope
    if (tid < 256){
      const int og = tid >> 6, ob = (tid >> 2) & 15, oq = tid & 3;
      u32x4 v = *(const u32x4*)&hml[og][ob][oq*8];
      u16* hw = hmg + ((size_t)(t&1)*NBG + bg)*(4*16*HH)
                    + (og*16 + ob)*HH + k0 + oq*8;
      st16_sys(hw, v);
    }
    asm volatile("s_waitcnt vmcnt(0)" ::: "memory");  // hm durable at MALL
    __syncthreads();
    if (tid == 0)
      __hip_atomic_fetch_add(&cnt[bg*TT + t], 1u, __ATOMIC_RELAXED,
                             __HIP_MEMORY_SCOPE_AGENT);
  }
}

// ---------------------------------------------------------------------------
extern "C" void kernel_launch(void* const* d_in, const int* in_sizes, int n_in,
                              void* d_out, int out_size, void* d_ws, size_t ws_size,
                              hipStream_t stream){
  const float* input   = (const float*)d_in[0];
  const float* ux      = (const float*)d_in[1];
  const float* uh      = (const float*)d_in[2];
  const float* p_logit = (const float*)d_in[3];
  const float* Wx      = (const float*)d_in[4];
  const float* bx      = (const float*)d_in[5];
  const float* Wh      = (const float*)d_in[6];
  const float* bh      = (const float*)d_in[7];

  char* ws = (char*)d_ws;
  const size_t o_zx  = 0;                        // 4*B*D f32      = 524288
  const size_t o_zh  = o_zx  + 524288;           // 4*B*H f32      = 1048576
  const size_t o_b   = o_zh  + 1048576;          // 4*H f32        = 8192
  const size_t o_wxb = o_b   + 8192;             // 4*H*D bf16     = 1048576
  const size_t o_whb = o_wxb + 1048576;          // 4*H*H bf16     = 2097152
  const size_t o_xim = o_whb + 2097152;          // T*4*B*D bf16   = 134217728
  const size_t o_hmg = o_xim + 134217728;        // 2*8*4*16*H bf16= 1048576
  const size_t o_cnt = o_hmg + 2097152;          // 8*T u32        = 16384
  const size_t need  = o_cnt + 16384;
  if (ws_size < need) return;

  float* zx   = (float*)(ws + o_zx);
  float* zh   = (float*)(ws + o_zh);
  float* bias = (float*)(ws + o_b);
  u16*   wxb  = (u16*)(ws + o_wxb);
  u16*   whb  = (u16*)(ws + o_whb);
  u16*   xim  = (u16*)(ws + o_xim);
  u16*   hmg  = (u16*)(ws + o_hmg);
  u32*   cnt  = (u32*)(ws + o_cnt);

  float* out_hn = (float*)d_out;
  float* out_ht = out_hn + (size_t)TT*BB*HH;

  setup_kernel<<<7704, 256, 0, stream>>>(ux, uh, p_logit, bx, bh, Wx, Wh,
                                         zx, zh, bias, wxb, whb, cnt);
  xim_kernel<<<8192, 256, 0, stream>>>(input, zx, xim);
  lstm_persist<<<NBG*NKS, 512, 0, stream>>>(xim, whb, wxb, zh, bias,
                                            hmg, cnt, out_hn, out_ht);
}